// Round 16
// baseline (540.410 us; speedup 1.0000x reference)
//
#include <hip/hip_runtime.h>

// ---------- types ----------
typedef short short8 __attribute__((ext_vector_type(8)));   // 8 bf16 as i16
typedef float f32x4 __attribute__((ext_vector_type(4)));

#define GLOBAL_AS __attribute__((address_space(1)))
#define LDS_AS    __attribute__((address_space(3)))

__device__ __forceinline__ unsigned short f2bf(float f) {
    unsigned u = __builtin_bit_cast(unsigned, f);
    u += 0x7fffu + ((u >> 16) & 1u);          // round-to-nearest-even
    return (unsigned short)(u >> 16);
}

// ---------- convert kernels (memory-bound, vectorized) ----------
__global__ __launch_bounds__(256) void k_idx2bf(const int* __restrict__ idx,
                                                const float* __restrict__ cb,
                                                ushort* __restrict__ out, int n4) {
    int i = blockIdx.x * 256 + threadIdx.x;
    if (i >= n4) return;
    int4 v = reinterpret_cast<const int4*>(idx)[i];
    ushort4 o;
    o.x = f2bf(cb[v.x]); o.y = f2bf(cb[v.y]);
    o.z = f2bf(cb[v.z]); o.w = f2bf(cb[v.w]);
    reinterpret_cast<ushort4*>(out)[i] = o;
}

__global__ __launch_bounds__(256) void k_f2bf(const float* __restrict__ in,
                                              ushort* __restrict__ out, int n4) {
    int i = blockIdx.x * 256 + threadIdx.x;
    if (i >= n4) return;
    float4 v = reinterpret_cast<const float4*>(in)[i];
    ushort4 o;
    o.x = f2bf(v.x); o.y = f2bf(v.y); o.z = f2bf(v.z); o.w = f2bf(v.w);
    reinterpret_cast<ushort4*>(out)[i] = o;
}

// ---------- 256x256 bf16 gemm_bt: reads-after-barrier, unpinned ----------
// 512 thr = 8 waves (2M x 4N), per-wave 128x64, BK=64, 2 K-tile LDS dbuf.
// Phase p of tile t: { barrier; stage 1 region of tile t+1 -> OTHER buf;
//   setprio(1); ds_reads for THIS quadrant; MFMA quadrant; setprio(0);
//   [vm fence] }. NOTHING side-effecting sits between the reads and the
//   MFMAs -> the compiler interleaves read-issue + per-fragment counted
//   lgkm waits INTO the MFMA burst: LDS service overlaps the matrix pipe
//   within the phase (rounds 10-15 pinned reads before a clobbered barrier,
//   forcing LDS(2304cyc) + MFMA(2484cyc) to run as a SUM = measured 5062
//   cyc/tile; m201's 3297 ~= max). Barriers: 4/tile (was 8).
// Quadrants: ph1 Q(0,0)=A0*B0 (reads A0[8],B0[4]); ph2 Q(0,1)=A0*B1
//   (reads B1[4]); ph3 Q(1,0)=A1*B0 (reads A1[8] into aF, A0 dead);
//   ph4 Q(1,1)=A1*B1 (no reads).
// Stage slots (tile t -> buf[(t+1)&1]): ph1 AE, ph2 BE, ph3 AL, ph4 BL.
// Overwrite safety: each staged region's last reads are USED by an MFMA
//   that precedes a barrier preceding the stage (3-5 barrier distances);
//   load-hoisting is bounded above by the memory-clobbered vm fences, so
//   distances hold under compiler reordering. Same-phase stage vs reads
//   never touch the same buffer.
// Readiness ledger (vm(2)@end-ph1, vm(2)@end-ph4, both before a barrier):
//   steady outstanding after end-ph4 fence = {BL(t+1)}; end-ph1(t) fence
//   completes BL(t) before ph2's B1 reads; end-ph4(t) completes
//   AE,BE,AL(t+1) before ph1(t+1)'s A0/B0 and ph3's A1 reads. Prologue:
//   stage AE,BE,AL,BL(0) + vm(2) (leaves BL(0)). Tail t=63: vm(0)@ph1.
// Registers: 128 acc (AGPR) + 64 operands + ~20 addr (spill tell:
//   FETCH/WRITE_SIZE). Swizzle (0 conflicts, r3/r6-verified): linear LDS
//   dest + pre-swizzled global col (slot s of row r holds s^(r&7)) +
//   XOR-folded static read offsets (ds imm <= 47104 < 64K).

#define CH_AE(j) ((((j) & 8) << 1) | ((j) & 7))
#define CH_AL(j) (CH_AE(j) + 8)
#define CH_BE(j) ((((j) & 12) << 1) | ((j) & 3))
#define CH_BL(j) (CH_BE(j) + 4)

#define STAGE2(GB, LW, KB, CF) do {                                             \
    const int c0_ = CF(2 * w);                                                  \
    const int c1_ = CF(2 * w + 1);                                              \
    __builtin_amdgcn_global_load_lds(                                           \
        (const GLOBAL_AS void*)((GB) + (size_t)c0_ * 32768 + (KB)),             \
        (LDS_AS void*)((LW) + c0_ * 512), 16, 0, 0);                            \
    __builtin_amdgcn_global_load_lds(                                           \
        (const GLOBAL_AS void*)((GB) + (size_t)c1_ * 32768 + (KB)),             \
        (LDS_AS void*)((LW) + c1_ * 512), 16, 0, 0);                            \
} while (0)

// static-offset fragment reads: BUF/MH/NH literal tokens -> ds imm
#define READ_A(DST, BUF, MH) do {                                               \
    _Pragma("unroll")                                                           \
    for (int mi = 0; mi < 4; ++mi)                                              \
        DST[0][mi] = *reinterpret_cast<const short8*>(                          \
            sAc + ak0 + ((BUF) + (MH) * 8192 + mi * 2048));                     \
    _Pragma("unroll")                                                           \
    for (int mi = 0; mi < 4; ++mi)                                              \
        DST[1][mi] = *reinterpret_cast<const short8*>(                          \
            sAc + ak1 + ((BUF) + (MH) * 8192 + mi * 2048));                     \
} while (0)

#define READ_B(DST, BUF, NH) do {                                               \
    _Pragma("unroll")                                                           \
    for (int ni = 0; ni < 2; ++ni)                                              \
        DST[0][ni] = *reinterpret_cast<const short8*>(                          \
            sBc + bk0 + ((BUF) + (NH) * 4096 + ni * 2048));                     \
    _Pragma("unroll")                                                           \
    for (int ni = 0; ni < 2; ++ni)                                              \
        DST[1][ni] = *reinterpret_cast<const short8*>(                          \
            sBc + bk1 + ((BUF) + (NH) * 4096 + ni * 2048));                     \
} while (0)

#define MFMA16Q(MH, NH, AF, BF)                                                 \
    _Pragma("unroll")                                                           \
    for (int k2 = 0; k2 < 2; ++k2)                                              \
        _Pragma("unroll")                                                       \
        for (int mi = 0; mi < 4; ++mi)                                          \
            _Pragma("unroll")                                                   \
            for (int ni = 0; ni < 2; ++ni)                                      \
                acc[(MH) * 4 + mi][(NH) * 2 + ni] =                             \
                    __builtin_amdgcn_mfma_f32_16x16x32_bf16(                    \
                        AF[k2][mi], BF[k2][ni], acc[(MH) * 4 + mi][(NH) * 2 + ni], 0, 0, 0)

#define VMF(N) asm volatile("s_waitcnt vmcnt(" #N ")" ::: "memory")
#define BARB   __builtin_amdgcn_s_barrier()

// ph1: bar; stage; reads A0,B0; Q(0,0); fence vm(FN)
#define PH1F(BUF, FN, ...) do {                                                 \
    BARB;                                                                       \
    __VA_ARGS__;                                                                \
    __builtin_amdgcn_s_setprio(1);                                              \
    READ_A(aF, BUF, 0); READ_B(b0f, BUF, 0);                                    \
    MFMA16Q(0, 0, aF, b0f);                                                     \
    __builtin_amdgcn_s_setprio(0);                                              \
    VMF(FN);                                                                    \
} while (0)

// ph2: bar; stage; reads B1; Q(0,1)
#define PH2F(BUF, ...) do {                                                     \
    BARB;                                                                       \
    __VA_ARGS__;                                                                \
    __builtin_amdgcn_s_setprio(1);                                              \
    READ_B(b1f, BUF, 1);                                                        \
    MFMA16Q(0, 1, aF, b1f);                                                     \
    __builtin_amdgcn_s_setprio(0);                                              \
} while (0)

// ph3: bar; stage; reads A1 (into aF, A0 dead); Q(1,0)
#define PH3F(BUF, ...) do {                                                     \
    BARB;                                                                       \
    __VA_ARGS__;                                                                \
    __builtin_amdgcn_s_setprio(1);                                              \
    READ_A(aF, BUF, 1);                                                         \
    MFMA16Q(1, 0, aF, b0f);                                                     \
    __builtin_amdgcn_s_setprio(0);                                              \
} while (0)

// ph4: bar; stage; no reads; Q(1,1); fence vm(FN)
#define PH4F(FN, ...) do {                                                      \
    BARB;                                                                       \
    __VA_ARGS__;                                                                \
    __builtin_amdgcn_s_setprio(1);                                              \
    MFMA16Q(1, 1, aF, b1f);                                                     \
    __builtin_amdgcn_s_setprio(0);                                              \
    VMF(FN);                                                                    \
} while (0)

#define PH4NO(...) do {                                                         \
    BARB;                                                                       \
    __VA_ARGS__;                                                                \
    __builtin_amdgcn_s_setprio(1);                                              \
    MFMA16Q(1, 1, aF, b1f);                                                     \
    __builtin_amdgcn_s_setprio(0);                                              \
} while (0)

// EPI=0: C=bf16, val = acc * extra[row]; EPI=1: C=f32, val = acc + extra[col]
template <int EPI>
__global__ __launch_bounds__(512, 2) void gemm256(const ushort* __restrict__ A,
                                                  const ushort* __restrict__ B,
                                                  void* __restrict__ C,
                                                  const float* __restrict__ extra) {
    constexpr int K = 4096, N = 4096;
    __shared__ ushort sA[2][256 * 64];
    __shared__ ushort sB[2][256 * 64];

    const int tid  = threadIdx.x;
    const int w    = tid >> 6;
    const int lane = tid & 63;
    const int wm = w >> 2, wn = w & 3;

    // XCD-aware swizzle (nwg % 8 == 0 for both grids)
    const int nwg = gridDim.x;
    const int sw  = ((int)blockIdx.x & 7) * (nwg >> 3) + ((int)blockIdx.x >> 3);
    const int m0 = (sw >> 4) * 256;      // 16 tiles per N-row (N=4096)
    const int n0 = (sw & 15) * 256;

    // staging bases: lane geometry folded once (global col pre-swizzled:
    // slot (lane&7) of row (lane>>3 mod 8) holds logical slot (lane&7)^(lane>>3))
    const int srow8 = lane >> 3;
    const int scol  = (((lane & 7) ^ (lane >> 3)) * 8);   // ushorts
    const ushort* gAl = A + (size_t)m0 * K + srow8 * 4096 + scol;
    const ushort* gBl = B + (size_t)n0 * K + srow8 * 4096 + scol;

    // fragment geometry (16x16x32: row=lane&15, k=(lane>>4)*8)
    const int fr   = lane & 15;
    const int fkb  = ((lane >> 4) & 3) * 16;          // byte offset along K
    const int swb  = (fr & 7) << 4;                   // read-side slot XOR
    const int arow = wm * 128 + fr;
    const int brow = wn * 64 + fr;
    // XOR-folded static read offsets (k2 folded pre-XOR; imms don't touch b4-6)
    const char* sAc = (const char*)&sA[0][0];
    const char* sBc = (const char*)&sB[0][0];
    const int ak0 = (arow * 128 + 0  + fkb) ^ swb;
    const int ak1 = (arow * 128 + 64 + fkb) ^ swb;
    const int bk0 = (brow * 128 + 0  + fkb) ^ swb;
    const int bk1 = (brow * 128 + 64 + fkb) ^ swb;

    f32x4 acc[8][4];
#pragma unroll
    for (int i = 0; i < 8; ++i)
#pragma unroll
        for (int j = 0; j < 4; ++j) acc[i][j] = (f32x4){0.f, 0.f, 0.f, 0.f};

    short8 aF[2][4], b0f[2][2], b1f[2][2];

    // ---- prologue: stage tile0 (AE,BE,AL,BL = 8 loads); vm(2) completes
    // AE,BE,AL(0), leaves {BL(0)} = steady invariant. Loop ph1 supplies the
    // barrier (fence precedes it).
    STAGE2(gAl, sA[0], 0, CH_AE); STAGE2(gBl, sB[0], 0, CH_BE);
    STAGE2(gAl, sA[0], 0, CH_AL); STAGE2(gBl, sB[0], 0, CH_BL);
    VMF(2);

    // ---- steady pairs: tiles 0..61 ----
    for (int pr = 0; pr < 31; ++pr) {
        const int t = 2 * pr;
        const int kb1 = (t + 1) * 64, kb2 = (t + 2) * 64;
        // even tile t (buf0): stage tile t+1 -> buf1
        PH1F(0, 2, STAGE2(gAl, sA[1], kb1, CH_AE));
        PH2F(0,    STAGE2(gBl, sB[1], kb1, CH_BE));
        PH3F(0,    STAGE2(gAl, sA[1], kb1, CH_AL));
        PH4F(2,    STAGE2(gBl, sB[1], kb1, CH_BL));
        // odd tile t+1 (buf1): stage tile t+2 -> buf0
        PH1F(32768, 2, STAGE2(gAl, sA[0], kb2, CH_AE));
        PH2F(32768,    STAGE2(gBl, sB[0], kb2, CH_BE));
        PH3F(32768,    STAGE2(gAl, sA[0], kb2, CH_AL));
        PH4F(2,        STAGE2(gBl, sB[0], kb2, CH_BL));
    }
    {   // ---- tile 62 (buf0): stage tile 63 -> buf1 ----
        PH1F(0, 2, STAGE2(gAl, sA[1], 4032, CH_AE));
        PH2F(0,    STAGE2(gBl, sB[1], 4032, CH_BE));
        PH3F(0,    STAGE2(gAl, sA[1], 4032, CH_AL));
        PH4F(2,    STAGE2(gBl, sB[1], 4032, CH_BL));
        // ---- tile 63 (buf1): no stages; drain BL(63) at ph1 ----
        PH1F(32768, 0, ((void)0));
        PH2F(32768,    ((void)0));
        PH3F(32768,    ((void)0));
        PH4NO(((void)0));
    }

    // ---- epilogue: C/D layout col=lane&15, row=(lane>>4)*4+reg ----
    const int rb = m0 + wm * 128 + ((lane >> 4) * 4);
    const int cb = n0 + wn * 64 + (lane & 15);
    if (EPI == 0) {
        ushort* Cw = (ushort*)C;
#pragma unroll
        for (int mi = 0; mi < 8; ++mi) {
#pragma unroll
            for (int r = 0; r < 4; ++r) {
                const int row = rb + mi * 16 + r;
                const float s = extra[row];
#pragma unroll
                for (int ni = 0; ni < 4; ++ni)
                    Cw[(size_t)row * N + cb + ni * 16] = f2bf(acc[mi][ni][r] * s);
            }
        }
    } else {
        float* Cf = (float*)C;
#pragma unroll
        for (int ni = 0; ni < 4; ++ni) {
            const float b = extra[cb + ni * 16];
#pragma unroll
            for (int mi = 0; mi < 8; ++mi) {
#pragma unroll
                for (int r = 0; r < 4; ++r) {
                    const int row = rb + mi * 16 + r;
                    Cf[(size_t)row * N + cb + ni * 16] = acc[mi][ni][r] + b;
                }
            }
        }
    }
}

// ---------- launch ----------
extern "C" void kernel_launch(void* const* d_in, const int* in_sizes, int n_in,
                              void* d_out, int out_size, void* d_ws, size_t ws_size,
                              hipStream_t stream) {
    const float* x     = (const float*)d_in[0];   // (4,2048,4096) f32
    const int*   widx  = (const int*)  d_in[1];   // (4096,4096) i32
    const float* wscal = (const float*)d_in[2];   // (4096,)
    const float* bias  = (const float*)d_in[3];   // (4096,)
    const float* rot   = (const float*)d_in[4];   // (4096,4096) f32
    const float* cb    = (const float*)d_in[5];   // (16,)
    float* out = (float*)d_out;                   // (4,2048,4096) f32

    constexpr size_t IN_F = 4096, OUT_F = 4096, MTOK = 8192;
    char* ws = (char*)d_ws;
    ushort* wq   = (ushort*)(ws);                 // 32 MiB: codebook[idx] bf16
    ushort* rbuf = (ushort*)(ws + 33554432);      // 32 MiB: rotation bf16
    ushort* xb   = (ushort*)(ws + 67108864);      // 64 MiB: x bf16
    ushort* wb   = (ushort*)(ws + 134217728);     // 32 MiB: dequantized W bf16
    (void)ws_size; (void)in_sizes; (void)n_in; (void)out_size;

    // converts (memory-bound)
    {
        int n4 = (int)(OUT_F * IN_F / 4);
        k_idx2bf<<<n4 / 256, 256, 0, stream>>>(widx, cb, wq, n4);
        k_f2bf<<<n4 / 256, 256, 0, stream>>>(rot, rbuf, n4);
        int n4x = (int)(MTOK * IN_F / 4);
        k_f2bf<<<n4x / 256, 256, 0, stream>>>(x, xb, n4x);
    }

    // GEMM A: W[o,j] = scale[o] * sum_i Wq[o,i] R[j,i]   (M=4096 -> 256 wgs)
    gemm256<0><<<dim3(256), 512, 0, stream>>>(wq, rbuf, (void*)wb, wscal);

    // GEMM B: out[m,o] = sum_j x[m,j] W[o,j] + bias[o]   (M=8192 -> 512 wgs)
    gemm256<1><<<dim3(512), 512, 0, stream>>>(xb, wb, (void*)out, bias);
}

// Round 17
// 457.710 us; speedup vs baseline: 1.1807x; 1.1807x over previous
//
#include <hip/hip_runtime.h>

// ---------- types ----------
typedef short short8 __attribute__((ext_vector_type(8)));   // 8 bf16 as i16
typedef float f32x4 __attribute__((ext_vector_type(4)));

#define GLOBAL_AS __attribute__((address_space(1)))
#define LDS_AS    __attribute__((address_space(3)))

__device__ __forceinline__ unsigned short f2bf(float f) {
    unsigned u = __builtin_bit_cast(unsigned, f);
    u += 0x7fffu + ((u >> 16) & 1u);          // round-to-nearest-even
    return (unsigned short)(u >> 16);
}

// ---------- fused convert kernel (one launch; 3 grid-stride segments) -----
// seg0: widx (int32 x 16M) --cb gather--> wq bf16      units: 4M int4
// seg1: rot  f32 16M -> rbuf bf16                      units: 4M float4
// seg2: x    f32 32M -> xb bf16                        units: 8M float4
// 16M units total; 2048 blocks x 256 thr grid-stride; all boundaries are
// multiples of one block's stride-chunk -> wave-uniform branches.
__global__ __launch_bounds__(256) void k_convert_all(
        const int* __restrict__ widx, const float* __restrict__ cb,
        ushort* __restrict__ wq,
        const float* __restrict__ rot, ushort* __restrict__ rbuf,
        const float* __restrict__ x, ushort* __restrict__ xb) {
    const int N0 = 4194304, N1 = 4194304, N2 = 8388608;   // 4M/4M/8M units
    const int total = N0 + N1 + N2;
    const int stride = gridDim.x * 256;
    for (int i = blockIdx.x * 256 + threadIdx.x; i < total; i += stride) {
        if (i < N0) {
            int4 v = reinterpret_cast<const int4*>(widx)[i];
            ushort4 o;
            o.x = f2bf(cb[v.x]); o.y = f2bf(cb[v.y]);
            o.z = f2bf(cb[v.z]); o.w = f2bf(cb[v.w]);
            reinterpret_cast<ushort4*>(wq)[i] = o;
        } else if (i < N0 + N1) {
            int j = i - N0;
            float4 v = reinterpret_cast<const float4*>(rot)[j];
            ushort4 o;
            o.x = f2bf(v.x); o.y = f2bf(v.y); o.z = f2bf(v.z); o.w = f2bf(v.w);
            reinterpret_cast<ushort4*>(rbuf)[j] = o;
        } else {
            int j = i - N0 - N1;
            float4 v = reinterpret_cast<const float4*>(x)[j];
            ushort4 o;
            o.x = f2bf(v.x); o.y = f2bf(v.y); o.z = f2bf(v.z); o.w = f2bf(v.w);
            reinterpret_cast<ushort4*>(xb)[j] = o;
        }
    }
}

// ---------- 256x256 bf16 gemm_bt: round-12 structure (best measured) ------
// 512 thr = 8 waves (2M x 4N), per-wave 128x64, BK=64, 2 K-tile LDS dbuf.
// Per K-tile 4 quadrant phases; each phase reads its OWN MFMA operands
// (12/4/8/0 ds_read_b128, k2-major), stages 1 half-tile (2 gload_lds), then
// [ph1: lgkmcnt(8) throttle] -> barrier -> split counted lgkm -> setprio(1)
// -> 16 MFMA -> setprio(0) -> [ph4: vmcnt(6)] -> barrier.
// Stages (tile t, cur=t&1): ph1 AL(t+1)->buf[cur^1]; ph2 AE(t+2), ph3
// BE(t+2), ph4 BL(t+2) -> buf[cur]. vm(6)@ph4 completes tile t+1, leaves
// {AE,BE,BL}(t+2) in flight. Race-safety per region verified r6/r10.
// Registers: 128 acc (AGPR) + 64 operands + ~20 addr <= 256 at 2 blk-waves/
// SIMD. Swizzle (0 conflicts, r3-verified): linear LDS dest + pre-swizzled
// global col (slot s of row r holds s^(r&7)) + XOR-folded static offsets.

#define CH_AE(j) ((((j) & 8) << 1) | ((j) & 7))
#define CH_AL(j) (CH_AE(j) + 8)
#define CH_BE(j) ((((j) & 12) << 1) | ((j) & 3))
#define CH_BL(j) (CH_BE(j) + 4)

#define STAGE2(GB, LW, KB, CF) do {                                             \
    const int c0_ = CF(2 * w);                                                  \
    const int c1_ = CF(2 * w + 1);                                              \
    __builtin_amdgcn_global_load_lds(                                           \
        (const GLOBAL_AS void*)((GB) + (size_t)c0_ * 32768 + (KB)),             \
        (LDS_AS void*)((LW) + c0_ * 512), 16, 0, 0);                            \
    __builtin_amdgcn_global_load_lds(                                           \
        (const GLOBAL_AS void*)((GB) + (size_t)c1_ * 32768 + (KB)),             \
        (LDS_AS void*)((LW) + c1_ * 512), 16, 0, 0);                            \
} while (0)

// static-offset fragment reads (k2-major issue order): BUF/MH/NH literals
#define READ_A(DST, BUF, MH) do {                                               \
    _Pragma("unroll")                                                           \
    for (int mi = 0; mi < 4; ++mi)                                              \
        DST[0][mi] = *reinterpret_cast<const short8*>(                          \
            sAc + ak0 + ((BUF) * 32768 + (MH) * 8192 + mi * 2048));             \
    _Pragma("unroll")                                                           \
    for (int mi = 0; mi < 4; ++mi)                                              \
        DST[1][mi] = *reinterpret_cast<const short8*>(                          \
            sAc + ak1 + ((BUF) * 32768 + (MH) * 8192 + mi * 2048));             \
} while (0)

#define READ_B(DST, BUF, NH) do {                                               \
    _Pragma("unroll")                                                           \
    for (int ni = 0; ni < 2; ++ni)                                              \
        DST[0][ni] = *reinterpret_cast<const short8*>(                          \
            sBc + bk0 + ((BUF) * 32768 + (NH) * 4096 + ni * 2048));             \
    _Pragma("unroll")                                                           \
    for (int ni = 0; ni < 2; ++ni)                                              \
        DST[1][ni] = *reinterpret_cast<const short8*>(                          \
            sBc + bk1 + ((BUF) * 32768 + (NH) * 4096 + ni * 2048));             \
} while (0)

// MFMA sub-cluster: quadrant (MH,NH), k-half K2, rows MI_B..MI_E-1
#define MFMA_Q(MH, NH, K2, MI_B, MI_E, BF)                                      \
    _Pragma("unroll")                                                           \
    for (int mi = (MI_B); mi < (MI_E); ++mi)                                    \
        _Pragma("unroll")                                                       \
        for (int ni = 0; ni < 2; ++ni)                                          \
            acc[(MH) * 4 + mi][(NH) * 2 + ni] =                                 \
                __builtin_amdgcn_mfma_f32_16x16x32_bf16(                        \
                    aF[K2][mi], BF[K2][ni], acc[(MH) * 4 + mi][(NH) * 2 + ni], 0, 0, 0)

#define LG(N) do {                                                              \
    asm volatile("s_waitcnt lgkmcnt(" #N ")" ::: "memory");                     \
    __builtin_amdgcn_sched_barrier(0);                                          \
} while (0)

#define PHTOP do {                                                              \
    asm volatile("" ::: "memory");                                              \
    __builtin_amdgcn_s_barrier();                                               \
} while (0)

#define PH_END do {                                                             \
    __builtin_amdgcn_s_setprio(0);                                              \
    asm volatile("" ::: "memory");                                              \
    __builtin_amdgcn_s_barrier();                                               \
    asm volatile("" ::: "memory");                                              \
} while (0)

// ph1: reads B0(4)+A0(8); stage; lgkm(8) throttle; barrier; split waits 6/4/0
#define PH1S(BUF, ...) do {                                                     \
    READ_B(b0f, BUF, 0); READ_A(aF, BUF, 0);                                    \
    __VA_ARGS__;                                                                \
    asm volatile("s_waitcnt lgkmcnt(8)" ::: "memory");                          \
    PHTOP;                                                                      \
    LG(6); __builtin_amdgcn_s_setprio(1);                                       \
    MFMA_Q(0, 0, 0, 0, 2, b0f);                                                 \
    LG(4);                                                                      \
    MFMA_Q(0, 0, 0, 2, 4, b0f);                                                 \
    LG(0);                                                                      \
    MFMA_Q(0, 0, 1, 0, 4, b0f);                                                 \
    PH_END;                                                                     \
} while (0)

// ph2: reads B1(4); stage; barrier; split waits 2/0
#define PH2S(BUF, ...) do {                                                     \
    READ_B(b1f, BUF, 1);                                                        \
    __VA_ARGS__;                                                                \
    PHTOP;                                                                      \
    LG(2); __builtin_amdgcn_s_setprio(1);                                       \
    MFMA_Q(0, 1, 0, 0, 4, b1f);                                                 \
    LG(0);                                                                      \
    MFMA_Q(0, 1, 1, 0, 4, b1f);                                                 \
    PH_END;                                                                     \
} while (0)

// ph3: reads A1(8); stage; barrier; split waits 4/0
#define PH3S(BUF, ...) do {                                                     \
    READ_A(aF, BUF, 1);                                                         \
    __VA_ARGS__;                                                                \
    PHTOP;                                                                      \
    LG(4); __builtin_amdgcn_s_setprio(1);                                       \
    MFMA_Q(1, 0, 0, 0, 4, b0f);                                                 \
    LG(0);                                                                      \
    MFMA_Q(1, 0, 1, 0, 4, b0f);                                                 \
    PH_END;                                                                     \
} while (0)

// ph4: no reads; 16 MFMA straight; vm fence; barrier
#define PH4S(FN, ...) do {                                                      \
    __VA_ARGS__;                                                                \
    PHTOP;                                                                      \
    __builtin_amdgcn_s_setprio(1);                                              \
    MFMA_Q(1, 1, 0, 0, 4, b1f);                                                 \
    MFMA_Q(1, 1, 1, 0, 4, b1f);                                                 \
    __builtin_amdgcn_s_setprio(0);                                              \
    asm volatile("s_waitcnt vmcnt(" #FN ")" ::: "memory");                      \
    __builtin_amdgcn_s_barrier();                                               \
    asm volatile("" ::: "memory");                                              \
} while (0)

#define PH4SNF(...) do {                                                        \
    __VA_ARGS__;                                                                \
    PHTOP;                                                                      \
    __builtin_amdgcn_s_setprio(1);                                              \
    MFMA_Q(1, 1, 0, 0, 4, b1f);                                                 \
    MFMA_Q(1, 1, 1, 0, 4, b1f);                                                 \
    PH_END;                                                                     \
} while (0)

// EPI=0: C=bf16, val = acc * extra[row]; EPI=1: C=f32, val = acc + extra[col]
template <int EPI>
__global__ __launch_bounds__(512, 2) void gemm256(const ushort* __restrict__ A,
                                                  const ushort* __restrict__ B,
                                                  void* __restrict__ C,
                                                  const float* __restrict__ extra) {
    constexpr int K = 4096, N = 4096;
    __shared__ ushort sA[2][256 * 64];
    __shared__ ushort sB[2][256 * 64];

    const int tid  = threadIdx.x;
    const int w    = tid >> 6;
    const int lane = tid & 63;
    const int wm = w >> 2, wn = w & 3;

    // XCD-aware swizzle (nwg % 8 == 0 for both grids)
    const int nwg = gridDim.x;
    const int sw  = ((int)blockIdx.x & 7) * (nwg >> 3) + ((int)blockIdx.x >> 3);
    const int m0 = (sw >> 4) * 256;      // 16 tiles per N-row (N=4096)
    const int n0 = (sw & 15) * 256;

    // staging bases: lane geometry folded once (global col pre-swizzled:
    // slot (lane&7) of row (lane>>3 mod 8) holds logical slot (lane&7)^(lane>>3))
    const int srow8 = lane >> 3;
    const int scol  = (((lane & 7) ^ (lane >> 3)) * 8);   // ushorts
    const ushort* gAl = A + (size_t)m0 * K + srow8 * 4096 + scol;
    const ushort* gBl = B + (size_t)n0 * K + srow8 * 4096 + scol;

    // fragment geometry (16x16x32: row=lane&15, k=(lane>>4)*8)
    const int fr   = lane & 15;
    const int fkb  = ((lane >> 4) & 3) * 16;          // byte offset along K
    const int swb  = (fr & 7) << 4;                   // read-side slot XOR
    const int arow = wm * 128 + fr;
    const int brow = wn * 64 + fr;
    // XOR-folded static read offsets (k2 folded pre-XOR; imms don't touch b4-6)
    const char* sAc = (const char*)&sA[0][0];
    const char* sBc = (const char*)&sB[0][0];
    const int ak0 = (arow * 128 + 0  + fkb) ^ swb;
    const int ak1 = (arow * 128 + 64 + fkb) ^ swb;
    const int bk0 = (brow * 128 + 0  + fkb) ^ swb;
    const int bk1 = (brow * 128 + 64 + fkb) ^ swb;

    f32x4 acc[8][4];
#pragma unroll
    for (int i = 0; i < 8; ++i)
#pragma unroll
        for (int j = 0; j < 4; ++j) acc[i][j] = (f32x4){0.f, 0.f, 0.f, 0.f};

    short8 aF[2][4], b0f[2][2], b1f[2][2];

    // ---- prologue: stage t0 (AE,BE,BL,AL) + t1 (AE,BE,BL) = 14 loads ----
    STAGE2(gAl, sA[0], 0, CH_AE); STAGE2(gBl, sB[0], 0, CH_BE);
    STAGE2(gBl, sB[0], 0, CH_BL); STAGE2(gAl, sA[0], 0, CH_AL);
    STAGE2(gAl, sA[1], 64, CH_AE); STAGE2(gBl, sB[1], 64, CH_BE);
    STAGE2(gBl, sB[1], 64, CH_BL);
    asm volatile("s_waitcnt vmcnt(6)" ::: "memory");   // tile0 fully resident
    __builtin_amdgcn_s_barrier();
    asm volatile("" ::: "memory");

    // ---- steady pairs: tiles 0..61 (stage refs <= tile 63) ----
    for (int pr = 0; pr < 31; ++pr) {
        const int t = 2 * pr;
        const int kb1 = (t + 1) * 64, kb2 = (t + 2) * 64, kb3 = (t + 3) * 64;
        // even tile t (buf0)
        PH1S(0, STAGE2(gAl, sA[1], kb1, CH_AL));
        PH2S(0, STAGE2(gAl, sA[0], kb2, CH_AE));
        PH3S(0, STAGE2(gBl, sB[0], kb2, CH_BE));
        PH4S(6, STAGE2(gBl, sB[0], kb2, CH_BL));
        // odd tile t+1 (buf1)
        PH1S(1, STAGE2(gAl, sA[0], kb2, CH_AL));
        PH2S(1, STAGE2(gAl, sA[1], kb3, CH_AE));
        PH3S(1, STAGE2(gBl, sB[1], kb3, CH_BE));
        PH4S(6, STAGE2(gBl, sB[1], kb3, CH_BL));
    }
    {   // ---- tail: tile 62 (buf0): stage only AL(63); drain at ph4 ----
        PH1S(0, STAGE2(gAl, sA[1], 63 * 64, CH_AL));
        PH2S(0, ((void)0));
        PH3S(0, ((void)0));
        PH4S(0, ((void)0));
        // ---- tail: tile 63 (buf1): no staging, no fence ----
        PH1S(1, ((void)0));
        PH2S(1, ((void)0));
        PH3S(1, ((void)0));
        PH4SNF(((void)0));
    }

    // ---- epilogue: C/D layout col=lane&15, row=(lane>>4)*4+reg ----
    const int rb = m0 + wm * 128 + ((lane >> 4) * 4);
    const int cb = n0 + wn * 64 + (lane & 15);
    if (EPI == 0) {
        ushort* Cw = (ushort*)C;
#pragma unroll
        for (int mi = 0; mi < 8; ++mi) {
#pragma unroll
            for (int r = 0; r < 4; ++r) {
                const int row = rb + mi * 16 + r;
                const float s = extra[row];
#pragma unroll
                for (int ni = 0; ni < 4; ++ni)
                    Cw[(size_t)row * N + cb + ni * 16] = f2bf(acc[mi][ni][r] * s);
            }
        }
    } else {
        float* Cf = (float*)C;
#pragma unroll
        for (int ni = 0; ni < 4; ++ni) {
            const float b = extra[cb + ni * 16];
#pragma unroll
            for (int mi = 0; mi < 8; ++mi) {
#pragma unroll
                for (int r = 0; r < 4; ++r) {
                    const int row = rb + mi * 16 + r;
                    Cf[(size_t)row * N + cb + ni * 16] = acc[mi][ni][r] + b;
                }
            }
        }
    }
}

// ---------- launch ----------
extern "C" void kernel_launch(void* const* d_in, const int* in_sizes, int n_in,
                              void* d_out, int out_size, void* d_ws, size_t ws_size,
                              hipStream_t stream) {
    const float* x     = (const float*)d_in[0];   // (4,2048,4096) f32
    const int*   widx  = (const int*)  d_in[1];   // (4096,4096) i32
    const float* wscal = (const float*)d_in[2];   // (4096,)
    const float* bias  = (const float*)d_in[3];   // (4096,)
    const float* rot   = (const float*)d_in[4];   // (4096,4096) f32
    const float* cb    = (const float*)d_in[5];   // (16,)
    float* out = (float*)d_out;                   // (4,2048,4096) f32

    char* ws = (char*)d_ws;
    ushort* wq   = (ushort*)(ws);                 // 32 MiB: codebook[idx] bf16
    ushort* rbuf = (ushort*)(ws + 33554432);      // 32 MiB: rotation bf16
    ushort* xb   = (ushort*)(ws + 67108864);      // 64 MiB: x bf16
    ushort* wb   = (ushort*)(ws + 134217728);     // 32 MiB: dequantized W bf16
    (void)ws_size; (void)in_sizes; (void)n_in; (void)out_size;

    // fused converts: one launch, 2048 blocks grid-stride
    k_convert_all<<<2048, 256, 0, stream>>>(widx, cb, wq, rot, rbuf, x, xb);

    // GEMM A: W[o,j] = scale[o] * sum_i Wq[o,i] R[j,i]   (M=4096 -> 256 wgs)
    gemm256<0><<<dim3(256), 512, 0, stream>>>(wq, rbuf, (void*)wb, wscal);

    // GEMM B: out[m,o] = sum_j x[m,j] W[o,j] + bias[o]   (M=8192 -> 512 wgs)
    gemm256<1><<<dim3(512), 512, 0, stream>>>(xb, wb, (void*)out, bias);
}